// Round 9
// baseline (3022.702 us; speedup 1.0000x reference)
//
#include <hip/hip_runtime.h>
#include <hip/hip_fp16.h>

#define N_NODES 50000
#define N_EDGES 400000
#define NCLS 4
#define HID 32
#define HI 36                        // HID + IN_DIM
#define ROWS_P (N_NODES * NCLS)      // 200000 per-plane (n,c) rows
#define PADCAP 672000                // padded list capacity (E + ~3.5*N expected, 32-sigma safe)

// tanh(x) = 1 - 2/(exp(2x)+1); clamp avoids inf*0 NaN in the NR step.
__device__ __forceinline__ float fast_tanh(float x) {
    x = fminf(15.0f, fmaxf(-15.0f, x));
    float e = __expf(2.0f * x);
    float d = 1.0f + e;
    float r = __builtin_amdgcn_rcpf(d);
    r = r * (2.0f - d * r);   // one Newton step
    return 1.0f - 2.0f * r;
}

union F4H8 { float4 f4; __half2 h2[4]; };

// Per plane: m[n][c][0:32] = tanh(x @ inW + inb), m[n][c][32:36] = x (same across c)
__global__ void k_init(const float* __restrict__ x, const float* __restrict__ W,
                       const float* __restrict__ b, float* __restrict__ m) {
    unsigned t = blockIdx.x * 256 + threadIdx.x;
    if (t >= N_NODES * HI) return;
    unsigned idx = t % HI;
    unsigned n   = t / HI;
    float x0 = x[n * 4 + 0], x1 = x[n * 4 + 1];
    float x2 = x[n * 4 + 2], x3 = x[n * 4 + 3];
    float val;
    if (idx < 32) {
        float a = b[idx];
        a += x0 * W[idx] + x1 * W[32 + idx] + x2 * W[64 + idx] + x3 * W[96 + idx];
        val = fast_tanh(a);
    } else {
        val = (idx == 32) ? x0 : (idx == 33) ? x1 : (idx == 34) ? x2 : x3;
    }
    float* dst = m + (size_t)n * (NCLS * HI) + idx;
    dst[0] = val; dst[HI] = val; dst[2 * HI] = val; dst[3 * HI] = val;
}

// ---------------- CSR build (per plane, once) ----------------
__global__ void k_hist(const int* __restrict__ rowI, const int* __restrict__ colI,
                       int* __restrict__ inCnt, int* __restrict__ outCnt) {
    unsigned e = blockIdx.x * 256 + threadIdx.x;
    if (e >= N_EDGES) return;
    atomicAdd(&inCnt[colI[e]], 1);
    atomicAdd(&outCnt[rowI[e]], 1);
}

// Exclusive scan. block 0: raw in -> inOffRaw; block 1: padded-8 in -> pinOff;
// block 2: padded-8 out -> poutOff.
__global__ void k_scan(const int* __restrict__ inCnt, const int* __restrict__ outCnt,
                       int* __restrict__ inOffRaw, int* __restrict__ pinOff,
                       int* __restrict__ poutOff) {
    const int* cnt = (blockIdx.x == 2) ? outCnt : inCnt;
    int* off = (blockIdx.x == 0) ? inOffRaw : (blockIdx.x == 1) ? pinOff : poutOff;
    bool pad = blockIdx.x != 0;
    __shared__ int sh[16];
    __shared__ int carry;
    int tid = threadIdx.x;            // 1024
    int lane = tid & 63, wid = tid >> 6;
    if (tid == 0) carry = 0;
    __syncthreads();
    for (int base = 0; base < N_NODES; base += 1024) {
        int i = base + tid;
        int v = (i < N_NODES) ? cnt[i] : 0;
        if (pad) v = (v + 7) & ~7;
        int val = v;
#pragma unroll
        for (int d = 1; d < 64; d <<= 1) {
            int t = __shfl_up(val, d, 64);
            if (lane >= d) val += t;
        }
        if (lane == 63) sh[wid] = val;
        __syncthreads();
        if (tid < 16) {
            int s = sh[tid];
#pragma unroll
            for (int d = 1; d < 16; d <<= 1) {
                int t = __shfl_up(s, d, 16);
                if (tid >= d) s += t;
            }
            sh[tid] = s;
        }
        __syncthreads();
        int waveOff = (wid == 0) ? 0 : sh[wid - 1];
        int incl = val + waveOff + carry;
        if (i < N_NODES) off[i] = incl - v;
        __syncthreads();
        if (tid == 1023) carry = incl;
        __syncthreads();
    }
    if (tid == 0) off[N_NODES] = carry;
}

// Dense in-CSR entry for k_edge: inL2[dense]=(row|col<<16, piP), poPA[dense]=poP,
// eArr[dense]=e. Padded gather arrays: inPrt[piP]=row, outPrt[poP]=col
// (pad slots stay 0 from the per-plane memset).
__global__ void k_fill(const int* __restrict__ rowI, const int* __restrict__ colI,
                       const int* __restrict__ inOffRaw, const int* __restrict__ pinOff,
                       const int* __restrict__ poutOff,
                       int* __restrict__ inCur, int* __restrict__ outCur,
                       int2* __restrict__ inL2, int* __restrict__ poPA,
                       int* __restrict__ eArr,
                       unsigned short* __restrict__ inPrt,
                       unsigned short* __restrict__ outPrt) {
    unsigned e = blockIdx.x * 256 + threadIdx.x;
    if (e >= N_EDGES) return;
    int r = rowI[e], cn = colI[e];
    int liIn  = atomicAdd(&inCur[cn], 1);
    int liOut = atomicAdd(&outCur[r], 1);
    int dense = inOffRaw[cn] + liIn;
    int piP   = pinOff[cn] + liIn;
    int poP   = poutOff[r] + liOut;
    inL2[dense] = make_int2(r | (cn << 16), piP);
    poPA[dense] = poP;
    eArr[dense] = (int)e;
    inPrt[piP]  = (unsigned short)r;
    outPrt[poP] = (unsigned short)cn;
}

// ---------------- per-iteration kernels ----------------

// Column-resident GEMM, scratch-free: thread owns one output column, wcol[36]
// in VGPRs (constant-indexed, no pointer casts), loops rows with wave-broadcast
// float4 m loads feeding FMAs directly. RPB rows per block.
template <int NSUB>
__global__ void k_gemm(const float* __restrict__ m,
                       const float* __restrict__ W0, const float* __restrict__ W1,
                       const float* __restrict__ W2, const float* __restrict__ W3,
                       __half* __restrict__ o0, __half* __restrict__ o1,
                       __half* __restrict__ o2, __half* __restrict__ o3) {
    constexpr int COLS = NSUB * 32;       // 128 (u|v|p|q) or 64 (u|v)
    constexpr int HALVES = 256 / COLS;    // 2 or 4
    constexpr int RPB = 32;
    unsigned tid = threadIdx.x;
    unsigned o = tid % COLS, half = tid / COLS;
    unsigned sub = o >> 5, oo = o & 31;
    const float* W = (sub == 0) ? W0 : (sub == 1) ? W1 : (sub == 2) ? W2 : W3;
    __half* dst    = (sub == 0) ? o0 : (sub == 1) ? o1 : (sub == 2) ? o2 : o3;
    float wcol[36];
#pragma unroll
    for (int k = 0; k < 36; ++k) wcol[k] = W[k * 32 + oo];
    unsigned rend = blockIdx.x * RPB + RPB;
    for (unsigned r = blockIdx.x * RPB + half; r < rend; r += HALVES) {
        const float4* m4 = reinterpret_cast<const float4*>(m + (size_t)r * HI);
        float acc = 0.f;
#pragma unroll
        for (int t = 0; t < 9; ++t) {
            float4 mv = m4[t];
            acc += mv.x * wcol[4 * t + 0];
            acc += mv.y * wcol[4 * t + 1];
            acc += mv.z * wcol[4 * t + 2];
            acc += mv.w * wcol[4 * t + 3];
        }
        dst[(size_t)r * 32 + oo] = __float2half_rn(acc);
    }
}

// Edges in in-CSR order (grouped by col -> u side L1-resident).
// Per (idx,c): s = tanh(sum_o tanh(u[col]+v[row]+b1)*w2 + b2); softmax over c (4 lanes).
template <bool FINAL>
__global__ void k_edge(const int2* __restrict__ inL2, const int* __restrict__ poPA,
                       const int* __restrict__ eArr,
                       const __half* __restrict__ u, const __half* __restrict__ v,
                       const float* __restrict__ b1, const float* __restrict__ w2,
                       const float* __restrict__ b2,
                       float* __restrict__ eaIn, float* __restrict__ eaOut,
                       float* __restrict__ dst) {
    unsigned g   = blockIdx.x * 256 + threadIdx.x;   // exact grid: E*4
    unsigned c   = g & 3;
    unsigned idx = g >> 2;
    int2 ent = inL2[idx];
    unsigned rc  = (unsigned)ent.x;
    unsigned row = rc & 0xFFFFu, col = rc >> 16;
    const float4* u4 = reinterpret_cast<const float4*>(u + (col * 4 + c) * 32);
    const float4* v4 = reinterpret_cast<const float4*>(v + (row * 4 + c) * 32);
    float t2 = b2[0];
#pragma unroll
    for (int i = 0; i < 4; ++i) {          // 4 x (16B = 8 halves)
        F4H8 U, V; U.f4 = u4[i]; V.f4 = v4[i];
#pragma unroll
        for (int jj = 0; jj < 4; ++jj) {
            float2 uf = __half22float2(U.h2[jj]);
            float2 vf = __half22float2(V.h2[jj]);
            int o = i * 8 + jj * 2;
            t2 += fast_tanh(uf.x + vf.x + b1[o])     * w2[o];
            t2 += fast_tanh(uf.y + vf.y + b1[o + 1]) * w2[o + 1];
        }
    }
    float s  = fast_tanh(t2);
    float m1 = fmaxf(s, __shfl_xor(s, 1, 4));
    float mx = fmaxf(m1, __shfl_xor(m1, 2, 4));
    float ex = __expf(s - mx);
    float sm = ex + __shfl_xor(ex, 1, 4);
    sm = sm + __shfl_xor(sm, 2, 4);
    float val = ex / sm;
    if (FINAL) {
        dst[(unsigned)eArr[idx] * 4 + c] = val;
    } else {
        eaIn[(unsigned)ent.y * 4 + c] = val;
        eaOut[(unsigned)poPA[idx] * 4 + c] = val;
    }
}

// Fused node net, padded batch-8 gathers (no conditionals in the hot loop).
// h = m@C + nb1 + sum_in eaIn*p[prt] + sum_out eaOut*q[prt];
// H = tanh(tanh(h) @ nW2 + nb2) -> m[row][0:32] in place. 8 rows x 32 lanes.
__global__ void k_node(float* __restrict__ m,
                       const __half* __restrict__ p, const __half* __restrict__ q,
                       const float* __restrict__ eaIn, const float* __restrict__ eaOut,
                       const int* __restrict__ pinOff, const int* __restrict__ poutOff,
                       const unsigned short* __restrict__ inPrt,
                       const unsigned short* __restrict__ outPrt,
                       const float* __restrict__ WC, const float* __restrict__ nb1,
                       const float* __restrict__ nW2, const float* __restrict__ nb2) {
    __shared__ float sC[36 * 32];
    __shared__ float sW2[32 * 32];
    __shared__ float tb[8 * 33];
    unsigned tid = threadIdx.x;
    for (unsigned i = tid; i < 36 * 32; i += 256) sC[i] = WC[i];
    for (unsigned i = tid; i < 32 * 32; i += 256) sW2[i] = nW2[i];
    unsigned rl = tid >> 5, k = tid & 31;
    unsigned row = blockIdx.x * 8 + rl;   // flat (n*4 + c)
    unsigned n = row >> 2, c = row & 3;
    const float4* m4 = reinterpret_cast<const float4*>(m + (size_t)row * HI);
    float mr[36];
#pragma unroll
    for (int i = 0; i < 9; ++i) {
        float4 v = m4[i];
        mr[4 * i] = v.x; mr[4 * i + 1] = v.y; mr[4 * i + 2] = v.z; mr[4 * i + 3] = v.w;
    }
    __syncthreads();
    float h = nb1[k];
#pragma unroll
    for (int kk = 0; kk < 36; ++kk) h += mr[kk] * sC[kk * 32 + k];

    unsigned gOff = c * 32 + k;
    {   // in-gather (padded length, multiple of 8; pad slots have prt=0, ea=0)
        int b1i = pinOff[n + 1];
        for (int b = pinOff[n]; b < b1i; b += 8) {
            unsigned prt[8]; float av[8];
#pragma unroll
            for (int i = 0; i < 8; ++i) {
                prt[i] = inPrt[b + i];
                av[i]  = eaIn[(unsigned)(b + i) * 4 + c];
            }
#pragma unroll
            for (int i = 0; i < 8; ++i)
                h += av[i] * __half2float(p[prt[i] * 128u + gOff]);
        }
    }
    {   // out-gather
        int b1o = poutOff[n + 1];
        for (int b = poutOff[n]; b < b1o; b += 8) {
            unsigned prt[8]; float av[8];
#pragma unroll
            for (int i = 0; i < 8; ++i) {
                prt[i] = outPrt[b + i];
                av[i]  = eaOut[(unsigned)(b + i) * 4 + c];
            }
#pragma unroll
            for (int i = 0; i < 8; ++i)
                h += av[i] * __half2float(q[prt[i] * 128u + gOff]);
        }
    }
    float t = fast_tanh(h);
    tb[rl * 33 + k] = t;
    __syncthreads();
    float hh = nb2[k];
#pragma unroll
    for (int kk = 0; kk < 32; ++kk) hh += tb[rl * 33 + kk] * sW2[kk * 32 + k];
    m[(size_t)row * HI + k] = fast_tanh(hh);
}

extern "C" void kernel_launch(void* const* d_in, const int* in_sizes, int n_in,
                              void* d_out, int out_size, void* d_ws, size_t ws_size,
                              hipStream_t stream) {
    const float* x   = (const float*)d_in[0];
    const int*   ei  = (const int*)d_in[1];
    const float* inW = (const float*)d_in[2];
    const float* inb = (const float*)d_in[3];
    const float* eW1 = (const float*)d_in[4];
    const float* eb1 = (const float*)d_in[5];
    const float* eW2 = (const float*)d_in[6];
    const float* eb2 = (const float*)d_in[7];
    const float* nW1 = (const float*)d_in[8];
    const float* nb1 = (const float*)d_in[9];
    const float* nW2 = (const float*)d_in[10];
    const float* nb2 = (const float*)d_in[11];
    float* out = (float*)d_out;

    // Workspace (~112 MB): m 28.8 | u,v,p,q fp16 51.2 | eaIn/eaOut 21.5 |
    // inL2 3.2 | poPA 1.6 | eArr 1.6 | prt u16 2.7 | offsets/counts ~1.0
    float*  m     = (float*)d_ws;
    __half* u     = (__half*)(m + (size_t)ROWS_P * HI);
    __half* v     = u + (size_t)ROWS_P * 32;
    __half* p     = v + (size_t)ROWS_P * 32;
    __half* q     = p + (size_t)ROWS_P * 32;
    float*  eaIn  = (float*)(q + (size_t)ROWS_P * 32);
    float*  eaOut = eaIn + (size_t)PADCAP * 4;
    int2*   inL2  = (int2*)(eaOut + (size_t)PADCAP * 4);
    int*    poPA  = (int*)(inL2 + N_EDGES);
    int*    eArr  = poPA + N_EDGES;
    unsigned short* inPrt  = (unsigned short*)(eArr + N_EDGES);
    unsigned short* outPrt = inPrt + PADCAP;
    int*    inOffRaw = (int*)(outPrt + PADCAP);
    int*    pinOff   = inOffRaw + (N_NODES + 1);
    int*    poutOff  = pinOff + (N_NODES + 1);
    int*    inCur    = poutOff + (N_NODES + 1);
    int*    outCur   = inCur + N_NODES;

    const int gridE = (N_EDGES + 255) / 256;

    for (int j = 0; j < 3; ++j) {
        const int*   rowI = ei + (size_t)j * 2 * N_EDGES;
        const int*   colI = rowI + N_EDGES;
        const float* eW1j = eW1 + j * 72 * 32;
        const float* eb1j = eb1 + j * 32;
        const float* eW2j = eW2 + j * 32;
        const float* eb2j = eb2 + j;
        const float* nW1j = nW1 + j * 108 * 32;
        const float* nb1j = nb1 + j * 32;
        const float* nW2j = nW2 + j * 1024;
        const float* nb2j = nb2 + j * 32;

        // CSR build (padded)
        hipMemsetAsync(inCur, 0, 2 * N_NODES * sizeof(int), stream);
        k_hist<<<gridE, 256, 0, stream>>>(rowI, colI, inCur, outCur);
        k_scan<<<3, 1024, 0, stream>>>(inCur, outCur, inOffRaw, pinOff, poutOff);
        hipMemsetAsync(inCur, 0, 2 * N_NODES * sizeof(int), stream);
        hipMemsetAsync(inPrt, 0, 2 * (size_t)PADCAP * sizeof(unsigned short), stream);
        hipMemsetAsync(eaIn, 0, 2 * (size_t)PADCAP * 4 * sizeof(float), stream);
        k_fill<<<gridE, 256, 0, stream>>>(rowI, colI, inOffRaw, pinOff, poutOff,
                                          inCur, outCur, inL2, poPA, eArr, inPrt, outPrt);

        k_init<<<(N_NODES * HI + 255) / 256, 256, 0, stream>>>(
            x + (size_t)j * N_NODES * 4, inW + j * 128, inb + j * 32, m);

        for (int it = 0; it < 3; ++it) {
            k_gemm<4><<<ROWS_P / 32, 256, 0, stream>>>(
                m, eW1j, eW1j + 36 * 32, nW1j, nW1j + 36 * 32, u, v, p, q);
            k_edge<false><<<N_EDGES * 4 / 256, 256, 0, stream>>>(
                inL2, poPA, eArr, u, v, eb1j, eW2j, eb2j, eaIn, eaOut, nullptr);
            k_node<<<ROWS_P / 8, 256, 0, stream>>>(m, p, q, eaIn, eaOut,
                                                   pinOff, poutOff, inPrt, outPrt,
                                                   nW1j + 72 * 32, nb1j, nW2j, nb2j);
        }
        k_gemm<2><<<ROWS_P / 32, 256, 0, stream>>>(
            m, eW1j, eW1j + 36 * 32, eW1j, eW1j, u, v, u, v);
        k_edge<true><<<N_EDGES * 4 / 256, 256, 0, stream>>>(
            inL2, poPA, eArr, u, v, eb1j, eW2j, eb2j, nullptr, nullptr,
            out + (size_t)j * N_EDGES * 4);
    }
}

// Round 10
// 2176.197 us; speedup vs baseline: 1.3890x; 1.3890x over previous
//
#include <hip/hip_runtime.h>
#include <hip/hip_fp16.h>

#define N_NODES 50000
#define N_EDGES 400000
#define NCLS 4
#define HID 32
#define HI 36                        // HID + IN_DIM
#define ROWS_P (N_NODES * NCLS)      // 200000 per-plane (n,c) rows
#define PADCAP 672000                // padded list capacity (E + ~3.5*N expected, 32-sigma safe)

// tanh(x) = 1 - 2/(exp(2x)+1); clamp avoids inf*0 NaN in the NR step.
__device__ __forceinline__ float fast_tanh(float x) {
    x = fminf(15.0f, fmaxf(-15.0f, x));
    float e = __expf(2.0f * x);
    float d = 1.0f + e;
    float r = __builtin_amdgcn_rcpf(d);
    r = r * (2.0f - d * r);   // one Newton step
    return 1.0f - 2.0f * r;
}

union F4H8 { float4 f4; __half2 h2[4]; };

// Per plane: m[n][c][0:32] = tanh(x @ inW + inb), m[n][c][32:36] = x (same across c)
__global__ void k_init(const float* __restrict__ x, const float* __restrict__ W,
                       const float* __restrict__ b, float* __restrict__ m) {
    unsigned t = blockIdx.x * 256 + threadIdx.x;
    if (t >= N_NODES * HI) return;
    unsigned idx = t % HI;
    unsigned n   = t / HI;
    float x0 = x[n * 4 + 0], x1 = x[n * 4 + 1];
    float x2 = x[n * 4 + 2], x3 = x[n * 4 + 3];
    float val;
    if (idx < 32) {
        float a = b[idx];
        a += x0 * W[idx] + x1 * W[32 + idx] + x2 * W[64 + idx] + x3 * W[96 + idx];
        val = fast_tanh(a);
    } else {
        val = (idx == 32) ? x0 : (idx == 33) ? x1 : (idx == 34) ? x2 : x3;
    }
    float* dst = m + (size_t)n * (NCLS * HI) + idx;
    dst[0] = val; dst[HI] = val; dst[2 * HI] = val; dst[3 * HI] = val;
}

// ---------------- CSR build (per plane, once) ----------------
__global__ void k_hist(const int* __restrict__ rowI, const int* __restrict__ colI,
                       int* __restrict__ inCnt, int* __restrict__ outCnt) {
    unsigned e = blockIdx.x * 256 + threadIdx.x;
    if (e >= N_EDGES) return;
    atomicAdd(&inCnt[colI[e]], 1);
    atomicAdd(&outCnt[rowI[e]], 1);
}

// Exclusive scan. block 0: raw in -> inOffRaw; block 1: padded-8 in -> pinOff;
// block 2: padded-8 out -> poutOff.
__global__ void k_scan(const int* __restrict__ inCnt, const int* __restrict__ outCnt,
                       int* __restrict__ inOffRaw, int* __restrict__ pinOff,
                       int* __restrict__ poutOff) {
    const int* cnt = (blockIdx.x == 2) ? outCnt : inCnt;
    int* off = (blockIdx.x == 0) ? inOffRaw : (blockIdx.x == 1) ? pinOff : poutOff;
    bool pad = blockIdx.x != 0;
    __shared__ int sh[16];
    __shared__ int carry;
    int tid = threadIdx.x;            // 1024
    int lane = tid & 63, wid = tid >> 6;
    if (tid == 0) carry = 0;
    __syncthreads();
    for (int base = 0; base < N_NODES; base += 1024) {
        int i = base + tid;
        int v = (i < N_NODES) ? cnt[i] : 0;
        if (pad) v = (v + 7) & ~7;
        int val = v;
#pragma unroll
        for (int d = 1; d < 64; d <<= 1) {
            int t = __shfl_up(val, d, 64);
            if (lane >= d) val += t;
        }
        if (lane == 63) sh[wid] = val;
        __syncthreads();
        if (tid < 16) {
            int s = sh[tid];
#pragma unroll
            for (int d = 1; d < 16; d <<= 1) {
                int t = __shfl_up(s, d, 16);
                if (tid >= d) s += t;
            }
            sh[tid] = s;
        }
        __syncthreads();
        int waveOff = (wid == 0) ? 0 : sh[wid - 1];
        int incl = val + waveOff + carry;
        if (i < N_NODES) off[i] = incl - v;
        __syncthreads();
        if (tid == 1023) carry = incl;
        __syncthreads();
    }
    if (tid == 0) off[N_NODES] = carry;
}

// Dense in-CSR entry for k_edge: inL2[dense]=(row|col<<16, piP), poPA[dense]=poP,
// eArr[dense]=e. Padded gather arrays: inPrt[piP]=row, outPrt[poP]=col
// (pad slots stay 0 from the per-plane memset).
__global__ void k_fill(const int* __restrict__ rowI, const int* __restrict__ colI,
                       const int* __restrict__ inOffRaw, const int* __restrict__ pinOff,
                       const int* __restrict__ poutOff,
                       int* __restrict__ inCur, int* __restrict__ outCur,
                       int2* __restrict__ inL2, int* __restrict__ poPA,
                       int* __restrict__ eArr,
                       unsigned short* __restrict__ inPrt,
                       unsigned short* __restrict__ outPrt) {
    unsigned e = blockIdx.x * 256 + threadIdx.x;
    if (e >= N_EDGES) return;
    int r = rowI[e], cn = colI[e];
    int liIn  = atomicAdd(&inCur[cn], 1);
    int liOut = atomicAdd(&outCur[r], 1);
    int dense = inOffRaw[cn] + liIn;
    int piP   = pinOff[cn] + liIn;
    int poP   = poutOff[r] + liOut;
    inL2[dense] = make_int2(r | (cn << 16), piP);
    poPA[dense] = poP;
    eArr[dense] = (int)e;
    inPrt[piP]  = (unsigned short)r;
    outPrt[poP] = (unsigned short)cn;
}

// ---------------- per-iteration kernels ----------------

// LDS-staged column-resident GEMM: block stages its 32 contiguous m-rows into
// LDS (one coalesced float4 pass), each thread owns one output column with
// wcol[36] register-resident, inner loop reads broadcast ds_read_b128 (short
// latency, 16 rows of ILP) -> no global latency in the hot loop.
template <int NSUB>
__global__ void k_gemm(const float* __restrict__ m,
                       const float* __restrict__ W0, const float* __restrict__ W1,
                       const float* __restrict__ W2, const float* __restrict__ W3,
                       __half* __restrict__ o0, __half* __restrict__ o1,
                       __half* __restrict__ o2, __half* __restrict__ o3) {
    constexpr int COLS = NSUB * 32;       // 128 (u|v|p|q) or 64 (u|v)
    constexpr int NG   = 256 / COLS;      // thread groups over rows
    constexpr int RPB  = 32;
    constexpr int RPG  = RPB / NG;        // rows per group
    __shared__ float sm[RPB * HI];        // 32 x 36 floats = 4.6 KB
    unsigned tid = threadIdx.x;
    unsigned r0  = blockIdx.x * RPB;
    // stage: rows r0..r0+31 are contiguous (1152 floats = 288 float4)
    {
        const float4* gsrc = reinterpret_cast<const float4*>(m + (size_t)r0 * HI);
        float4* ldst = reinterpret_cast<float4*>(sm);
        for (unsigned i = tid; i < RPB * HI / 4; i += 256) ldst[i] = gsrc[i];
    }
    unsigned o = tid % COLS, grp = tid / COLS;
    unsigned sub = o >> 5, oo = o & 31;
    const float* W = (sub == 0) ? W0 : (sub == 1) ? W1 : (sub == 2) ? W2 : W3;
    __half* dst    = (sub == 0) ? o0 : (sub == 1) ? o1 : (sub == 2) ? o2 : o3;
    float wcol[36];
#pragma unroll
    for (int k = 0; k < 36; ++k) wcol[k] = W[k * 32 + oo];
    __syncthreads();
#pragma unroll
    for (int i = 0; i < RPG; ++i) {
        unsigned rloc = grp * RPG + i;
        const float4* mv4 = reinterpret_cast<const float4*>(sm + rloc * HI);
        float acc = 0.f;
#pragma unroll
        for (int t = 0; t < 9; ++t) {
            float4 mv = mv4[t];
            acc += mv.x * wcol[4 * t + 0];
            acc += mv.y * wcol[4 * t + 1];
            acc += mv.z * wcol[4 * t + 2];
            acc += mv.w * wcol[4 * t + 3];
        }
        dst[(size_t)(r0 + rloc) * 32 + oo] = __float2half_rn(acc);
    }
}

// Edges in in-CSR order (grouped by col -> u side L1-resident).
// Per (idx,c): s = tanh(sum_o tanh(u[col]+v[row]+b1)*w2 + b2); softmax over c (4 lanes).
template <bool FINAL>
__global__ void k_edge(const int2* __restrict__ inL2, const int* __restrict__ poPA,
                       const int* __restrict__ eArr,
                       const __half* __restrict__ u, const __half* __restrict__ v,
                       const float* __restrict__ b1, const float* __restrict__ w2,
                       const float* __restrict__ b2,
                       float* __restrict__ eaIn, float* __restrict__ eaOut,
                       float* __restrict__ dst) {
    unsigned g   = blockIdx.x * 256 + threadIdx.x;   // exact grid: E*4
    unsigned c   = g & 3;
    unsigned idx = g >> 2;
    int2 ent = inL2[idx];
    unsigned rc  = (unsigned)ent.x;
    unsigned row = rc & 0xFFFFu, col = rc >> 16;
    const float4* u4 = reinterpret_cast<const float4*>(u + (col * 4 + c) * 32);
    const float4* v4 = reinterpret_cast<const float4*>(v + (row * 4 + c) * 32);
    float t2 = b2[0];
#pragma unroll
    for (int i = 0; i < 4; ++i) {          // 4 x (16B = 8 halves)
        F4H8 U, V; U.f4 = u4[i]; V.f4 = v4[i];
#pragma unroll
        for (int jj = 0; jj < 4; ++jj) {
            float2 uf = __half22float2(U.h2[jj]);
            float2 vf = __half22float2(V.h2[jj]);
            int o = i * 8 + jj * 2;
            t2 += fast_tanh(uf.x + vf.x + b1[o])     * w2[o];
            t2 += fast_tanh(uf.y + vf.y + b1[o + 1]) * w2[o + 1];
        }
    }
    float s  = fast_tanh(t2);
    float m1 = fmaxf(s, __shfl_xor(s, 1, 4));
    float mx = fmaxf(m1, __shfl_xor(m1, 2, 4));
    float ex = __expf(s - mx);
    float sm = ex + __shfl_xor(ex, 1, 4);
    sm = sm + __shfl_xor(sm, 2, 4);
    float val = ex / sm;
    if (FINAL) {
        dst[(unsigned)eArr[idx] * 4 + c] = val;
    } else {
        eaIn[(unsigned)ent.y * 4 + c] = val;
        eaOut[(unsigned)poPA[idx] * 4 + c] = val;
    }
}

// Fused node net, padded batch-8 gathers (no conditionals in the hot loop).
// h = m@C + nb1 + sum_in eaIn*p[prt] + sum_out eaOut*q[prt];
// H = tanh(tanh(h) @ nW2 + nb2) -> m[row][0:32] in place. 8 rows x 32 lanes.
__global__ void k_node(float* __restrict__ m,
                       const __half* __restrict__ p, const __half* __restrict__ q,
                       const float* __restrict__ eaIn, const float* __restrict__ eaOut,
                       const int* __restrict__ pinOff, const int* __restrict__ poutOff,
                       const unsigned short* __restrict__ inPrt,
                       const unsigned short* __restrict__ outPrt,
                       const float* __restrict__ WC, const float* __restrict__ nb1,
                       const float* __restrict__ nW2, const float* __restrict__ nb2) {
    __shared__ float sC[36 * 32];
    __shared__ float sW2[32 * 32];
    __shared__ float tb[8 * 33];
    unsigned tid = threadIdx.x;
    for (unsigned i = tid; i < 36 * 32; i += 256) sC[i] = WC[i];
    for (unsigned i = tid; i < 32 * 32; i += 256) sW2[i] = nW2[i];
    unsigned rl = tid >> 5, k = tid & 31;
    unsigned row = blockIdx.x * 8 + rl;   // flat (n*4 + c)
    unsigned n = row >> 2, c = row & 3;
    const float4* m4 = reinterpret_cast<const float4*>(m + (size_t)row * HI);
    float mr[36];
#pragma unroll
    for (int i = 0; i < 9; ++i) {
        float4 v = m4[i];
        mr[4 * i] = v.x; mr[4 * i + 1] = v.y; mr[4 * i + 2] = v.z; mr[4 * i + 3] = v.w;
    }
    __syncthreads();
    float h = nb1[k];
#pragma unroll
    for (int kk = 0; kk < 36; ++kk) h += mr[kk] * sC[kk * 32 + k];

    unsigned gOff = c * 32 + k;
    {   // in-gather (padded length, multiple of 8; pad slots have prt=0, ea=0)
        int b1i = pinOff[n + 1];
        for (int b = pinOff[n]; b < b1i; b += 8) {
            unsigned prt[8]; float av[8];
#pragma unroll
            for (int i = 0; i < 8; ++i) {
                prt[i] = inPrt[b + i];
                av[i]  = eaIn[(unsigned)(b + i) * 4 + c];
            }
#pragma unroll
            for (int i = 0; i < 8; ++i)
                h += av[i] * __half2float(p[prt[i] * 128u + gOff]);
        }
    }
    {   // out-gather
        int b1o = poutOff[n + 1];
        for (int b = poutOff[n]; b < b1o; b += 8) {
            unsigned prt[8]; float av[8];
#pragma unroll
            for (int i = 0; i < 8; ++i) {
                prt[i] = outPrt[b + i];
                av[i]  = eaOut[(unsigned)(b + i) * 4 + c];
            }
#pragma unroll
            for (int i = 0; i < 8; ++i)
                h += av[i] * __half2float(q[prt[i] * 128u + gOff]);
        }
    }
    float t = fast_tanh(h);
    tb[rl * 33 + k] = t;
    __syncthreads();
    float hh = nb2[k];
#pragma unroll
    for (int kk = 0; kk < 32; ++kk) hh += tb[rl * 33 + kk] * sW2[kk * 32 + k];
    m[(size_t)row * HI + k] = fast_tanh(hh);
}

extern "C" void kernel_launch(void* const* d_in, const int* in_sizes, int n_in,
                              void* d_out, int out_size, void* d_ws, size_t ws_size,
                              hipStream_t stream) {
    const float* x   = (const float*)d_in[0];
    const int*   ei  = (const int*)d_in[1];
    const float* inW = (const float*)d_in[2];
    const float* inb = (const float*)d_in[3];
    const float* eW1 = (const float*)d_in[4];
    const float* eb1 = (const float*)d_in[5];
    const float* eW2 = (const float*)d_in[6];
    const float* eb2 = (const float*)d_in[7];
    const float* nW1 = (const float*)d_in[8];
    const float* nb1 = (const float*)d_in[9];
    const float* nW2 = (const float*)d_in[10];
    const float* nb2 = (const float*)d_in[11];
    float* out = (float*)d_out;

    // Workspace (~112 MB): m 28.8 | u,v,p,q fp16 51.2 | eaIn/eaOut 21.5 |
    // inL2 3.2 | poPA 1.6 | eArr 1.6 | prt u16 2.7 | offsets/counts ~1.0
    float*  m     = (float*)d_ws;
    __half* u     = (__half*)(m + (size_t)ROWS_P * HI);
    __half* v     = u + (size_t)ROWS_P * 32;
    __half* p     = v + (size_t)ROWS_P * 32;
    __half* q     = p + (size_t)ROWS_P * 32;
    float*  eaIn  = (float*)(q + (size_t)ROWS_P * 32);
    float*  eaOut = eaIn + (size_t)PADCAP * 4;
    int2*   inL2  = (int2*)(eaOut + (size_t)PADCAP * 4);
    int*    poPA  = (int*)(inL2 + N_EDGES);
    int*    eArr  = poPA + N_EDGES;
    unsigned short* inPrt  = (unsigned short*)(eArr + N_EDGES);
    unsigned short* outPrt = inPrt + PADCAP;
    int*    inOffRaw = (int*)(outPrt + PADCAP);
    int*    pinOff   = inOffRaw + (N_NODES + 1);
    int*    poutOff  = pinOff + (N_NODES + 1);
    int*    inCur    = poutOff + (N_NODES + 1);
    int*    outCur   = inCur + N_NODES;

    const int gridE = (N_EDGES + 255) / 256;

    for (int j = 0; j < 3; ++j) {
        const int*   rowI = ei + (size_t)j * 2 * N_EDGES;
        const int*   colI = rowI + N_EDGES;
        const float* eW1j = eW1 + j * 72 * 32;
        const float* eb1j = eb1 + j * 32;
        const float* eW2j = eW2 + j * 32;
        const float* eb2j = eb2 + j;
        const float* nW1j = nW1 + j * 108 * 32;
        const float* nb1j = nb1 + j * 32;
        const float* nW2j = nW2 + j * 1024;
        const float* nb2j = nb2 + j * 32;

        // CSR build (padded)
        hipMemsetAsync(inCur, 0, 2 * N_NODES * sizeof(int), stream);
        k_hist<<<gridE, 256, 0, stream>>>(rowI, colI, inCur, outCur);
        k_scan<<<3, 1024, 0, stream>>>(inCur, outCur, inOffRaw, pinOff, poutOff);
        hipMemsetAsync(inCur, 0, 2 * N_NODES * sizeof(int), stream);
        hipMemsetAsync(inPrt, 0, 2 * (size_t)PADCAP * sizeof(unsigned short), stream);
        hipMemsetAsync(eaIn, 0, 2 * (size_t)PADCAP * 4 * sizeof(float), stream);
        k_fill<<<gridE, 256, 0, stream>>>(rowI, colI, inOffRaw, pinOff, poutOff,
                                          inCur, outCur, inL2, poPA, eArr, inPrt, outPrt);

        k_init<<<(N_NODES * HI + 255) / 256, 256, 0, stream>>>(
            x + (size_t)j * N_NODES * 4, inW + j * 128, inb + j * 32, m);

        for (int it = 0; it < 3; ++it) {
            k_gemm<4><<<ROWS_P / 32, 256, 0, stream>>>(
                m, eW1j, eW1j + 36 * 32, nW1j, nW1j + 36 * 32, u, v, p, q);
            k_edge<false><<<N_EDGES * 4 / 256, 256, 0, stream>>>(
                inL2, poPA, eArr, u, v, eb1j, eW2j, eb2j, eaIn, eaOut, nullptr);
            k_node<<<ROWS_P / 8, 256, 0, stream>>>(m, p, q, eaIn, eaOut,
                                                   pinOff, poutOff, inPrt, outPrt,
                                                   nW1j + 72 * 32, nb1j, nW2j, nb2j);
        }
        k_gemm<2><<<ROWS_P / 32, 256, 0, stream>>>(
            m, eW1j, eW1j + 36 * 32, eW1j, eW1j, u, v, u, v);
        k_edge<true><<<N_EDGES * 4 / 256, 256, 0, stream>>>(
            inL2, poPA, eArr, u, v, eb1j, eW2j, eb2j, nullptr, nullptr,
            out + (size_t)j * N_EDGES * 4);
    }
}

// Round 11
// 1967.121 us; speedup vs baseline: 1.5366x; 1.1063x over previous
//
#include <hip/hip_runtime.h>
#include <hip/hip_fp16.h>

#define N_NODES 50000
#define N_EDGES 400000
#define NCLS 4
#define HID 32
#define HI 36                        // HID + IN_DIM
#define ROWS_P (N_NODES * NCLS)      // 200000 per-plane (n,c) rows
#define PADCAP 672000                // padded list capacity (E + ~3.5*N expected, 32-sigma safe)

// tanh(x) = 1 - 2/(exp(2x)+1); clamp avoids inf*0 NaN in the NR step.
__device__ __forceinline__ float fast_tanh(float x) {
    x = fminf(15.0f, fmaxf(-15.0f, x));
    float e = __expf(2.0f * x);
    float d = 1.0f + e;
    float r = __builtin_amdgcn_rcpf(d);
    r = r * (2.0f - d * r);   // one Newton step
    return 1.0f - 2.0f * r;
}

union F4H8 { float4 f4; __half2 h2[4]; };

// Per plane: m[n][c][0:32] = tanh(x @ inW + inb), m[n][c][32:36] = x (same across c)
__global__ void k_init(const float* __restrict__ x, const float* __restrict__ W,
                       const float* __restrict__ b, float* __restrict__ m) {
    unsigned t = blockIdx.x * 256 + threadIdx.x;
    if (t >= N_NODES * HI) return;
    unsigned idx = t % HI;
    unsigned n   = t / HI;
    float x0 = x[n * 4 + 0], x1 = x[n * 4 + 1];
    float x2 = x[n * 4 + 2], x3 = x[n * 4 + 3];
    float val;
    if (idx < 32) {
        float a = b[idx];
        a += x0 * W[idx] + x1 * W[32 + idx] + x2 * W[64 + idx] + x3 * W[96 + idx];
        val = fast_tanh(a);
    } else {
        val = (idx == 32) ? x0 : (idx == 33) ? x1 : (idx == 34) ? x2 : x3;
    }
    float* dst = m + (size_t)n * (NCLS * HI) + idx;
    dst[0] = val; dst[HI] = val; dst[2 * HI] = val; dst[3 * HI] = val;
}

// ---------------- CSR build (per plane, once) ----------------
__global__ void k_hist(const int* __restrict__ rowI, const int* __restrict__ colI,
                       int* __restrict__ inCnt, int* __restrict__ outCnt) {
    unsigned e = blockIdx.x * 256 + threadIdx.x;
    if (e >= N_EDGES) return;
    atomicAdd(&inCnt[colI[e]], 1);
    atomicAdd(&outCnt[rowI[e]], 1);
}

// Exclusive scan. block 0: raw in -> inOffRaw; block 1: padded-8 in -> pinOff;
// block 2: padded-8 out -> poutOff.
__global__ void k_scan(const int* __restrict__ inCnt, const int* __restrict__ outCnt,
                       int* __restrict__ inOffRaw, int* __restrict__ pinOff,
                       int* __restrict__ poutOff) {
    const int* cnt = (blockIdx.x == 2) ? outCnt : inCnt;
    int* off = (blockIdx.x == 0) ? inOffRaw : (blockIdx.x == 1) ? pinOff : poutOff;
    bool pad = blockIdx.x != 0;
    __shared__ int sh[16];
    __shared__ int carry;
    int tid = threadIdx.x;            // 1024
    int lane = tid & 63, wid = tid >> 6;
    if (tid == 0) carry = 0;
    __syncthreads();
    for (int base = 0; base < N_NODES; base += 1024) {
        int i = base + tid;
        int v = (i < N_NODES) ? cnt[i] : 0;
        if (pad) v = (v + 7) & ~7;
        int val = v;
#pragma unroll
        for (int d = 1; d < 64; d <<= 1) {
            int t = __shfl_up(val, d, 64);
            if (lane >= d) val += t;
        }
        if (lane == 63) sh[wid] = val;
        __syncthreads();
        if (tid < 16) {
            int s = sh[tid];
#pragma unroll
            for (int d = 1; d < 16; d <<= 1) {
                int t = __shfl_up(s, d, 16);
                if (tid >= d) s += t;
            }
            sh[tid] = s;
        }
        __syncthreads();
        int waveOff = (wid == 0) ? 0 : sh[wid - 1];
        int incl = val + waveOff + carry;
        if (i < N_NODES) off[i] = incl - v;
        __syncthreads();
        if (tid == 1023) carry = incl;
        __syncthreads();
    }
    if (tid == 0) off[N_NODES] = carry;
}

// Dense in-CSR entry for k_edge: inL2[dense]=(row|col<<16, piP), poPA[dense]=poP,
// eArr[dense]=e. Padded gather arrays: inPrt[piP]=row, outPrt[poP]=col
// (pad slots stay 0 from the per-plane memset).
__global__ void k_fill(const int* __restrict__ rowI, const int* __restrict__ colI,
                       const int* __restrict__ inOffRaw, const int* __restrict__ pinOff,
                       const int* __restrict__ poutOff,
                       int* __restrict__ inCur, int* __restrict__ outCur,
                       int2* __restrict__ inL2, int* __restrict__ poPA,
                       int* __restrict__ eArr,
                       unsigned short* __restrict__ inPrt,
                       unsigned short* __restrict__ outPrt) {
    unsigned e = blockIdx.x * 256 + threadIdx.x;
    if (e >= N_EDGES) return;
    int r = rowI[e], cn = colI[e];
    int liIn  = atomicAdd(&inCur[cn], 1);
    int liOut = atomicAdd(&outCur[r], 1);
    int dense = inOffRaw[cn] + liIn;
    int piP   = pinOff[cn] + liIn;
    int poP   = poutOff[r] + liOut;
    inL2[dense] = make_int2(r | (cn << 16), piP);
    poPA[dense] = poP;
    eArr[dense] = (int)e;
    inPrt[piP]  = (unsigned short)r;
    outPrt[poP] = (unsigned short)cn;
}

// ---------------- per-iteration kernels ----------------

// Fused 5-plane LDS-staged GEMM (320 threads): block stages 32 contiguous m-rows
// into LDS, each thread owns one of 160 output cols (u|v|p|q fp16, r fp32) with
// wcol[36] register-resident; 2 row-groups x 16 rows.
__global__ void k_gemm5(const float* __restrict__ m,
                        const float* __restrict__ eW1, const float* __restrict__ nW1,
                        __half* __restrict__ u, __half* __restrict__ v,
                        __half* __restrict__ p, __half* __restrict__ q,
                        float* __restrict__ r) {
    constexpr int RPB = 32;
    __shared__ float sm[RPB * HI];        // 4.6 KB
    unsigned tid = threadIdx.x;           // 320
    unsigned r0  = blockIdx.x * RPB;
    {
        const float4* gsrc = reinterpret_cast<const float4*>(m + (size_t)r0 * HI);
        float4* ldst = reinterpret_cast<float4*>(sm);
        for (unsigned i = tid; i < RPB * HI / 4; i += 320) ldst[i] = gsrc[i];
    }
    unsigned o = tid % 160, grp = tid / 160;   // grp in {0,1}
    unsigned sub = o >> 5, oo = o & 31;
    const float* W = (sub == 0) ? eW1 : (sub == 1) ? eW1 + 36 * 32 :
                     (sub == 2) ? nW1 : (sub == 3) ? nW1 + 36 * 32 : nW1 + 72 * 32;
    __half* dsth   = (sub == 0) ? u : (sub == 1) ? v : (sub == 2) ? p : q;
    float wcol[36];
#pragma unroll
    for (int k = 0; k < 36; ++k) wcol[k] = W[k * 32 + oo];
    __syncthreads();
#pragma unroll
    for (int i = 0; i < 16; ++i) {
        unsigned rloc = grp * 16 + i;
        const float4* mv4 = reinterpret_cast<const float4*>(sm + rloc * HI);
        float acc = 0.f;
#pragma unroll
        for (int t = 0; t < 9; ++t) {
            float4 mv = mv4[t];
            acc += mv.x * wcol[4 * t + 0];
            acc += mv.y * wcol[4 * t + 1];
            acc += mv.z * wcol[4 * t + 2];
            acc += mv.w * wcol[4 * t + 3];
        }
        size_t off = (size_t)(r0 + rloc) * 32 + oo;
        if (sub == 4) r[off] = acc;
        else          dsth[off] = __float2half_rn(acc);
    }
}

// Final-pass projection: u|v only (LDS-staged, 256 threads).
__global__ void k_gemm2(const float* __restrict__ m, const float* __restrict__ W0,
                        const float* __restrict__ W1,
                        __half* __restrict__ o0, __half* __restrict__ o1) {
    constexpr int RPB = 32;
    __shared__ float sm[RPB * HI];
    unsigned tid = threadIdx.x;
    unsigned r0  = blockIdx.x * RPB;
    {
        const float4* gsrc = reinterpret_cast<const float4*>(m + (size_t)r0 * HI);
        float4* ldst = reinterpret_cast<float4*>(sm);
        for (unsigned i = tid; i < RPB * HI / 4; i += 256) ldst[i] = gsrc[i];
    }
    unsigned o = tid % 64, grp = tid / 64;     // 4 row-groups of 8
    unsigned sub = o >> 5, oo = o & 31;
    const float* W = sub ? W1 : W0;
    __half* dst    = sub ? o1 : o0;
    float wcol[36];
#pragma unroll
    for (int k = 0; k < 36; ++k) wcol[k] = W[k * 32 + oo];
    __syncthreads();
#pragma unroll
    for (int i = 0; i < 8; ++i) {
        unsigned rloc = grp * 8 + i;
        const float4* mv4 = reinterpret_cast<const float4*>(sm + rloc * HI);
        float acc = 0.f;
#pragma unroll
        for (int t = 0; t < 9; ++t) {
            float4 mv = mv4[t];
            acc += mv.x * wcol[4 * t + 0];
            acc += mv.y * wcol[4 * t + 1];
            acc += mv.z * wcol[4 * t + 2];
            acc += mv.w * wcol[4 * t + 3];
        }
        dst[(size_t)(r0 + rloc) * 32 + oo] = __float2half_rn(acc);
    }
}

// Edges in in-CSR order (grouped by col -> u side L1-resident).
// Per (idx,c): s = tanh(sum_o tanh(u[col]+v[row]+b1)*w2 + b2); softmax over c (4 lanes).
template <bool FINAL>
__global__ void k_edge(const int2* __restrict__ inL2, const int* __restrict__ poPA,
                       const int* __restrict__ eArr,
                       const __half* __restrict__ u, const __half* __restrict__ v,
                       const float* __restrict__ b1, const float* __restrict__ w2,
                       const float* __restrict__ b2,
                       float* __restrict__ eaIn, float* __restrict__ eaOut,
                       float* __restrict__ dst) {
    unsigned g   = blockIdx.x * 256 + threadIdx.x;   // exact grid: E*4
    unsigned c   = g & 3;
    unsigned idx = g >> 2;
    int2 ent = inL2[idx];
    unsigned rc  = (unsigned)ent.x;
    unsigned row = rc & 0xFFFFu, col = rc >> 16;
    const float4* u4 = reinterpret_cast<const float4*>(u + (col * 4 + c) * 32);
    const float4* v4 = reinterpret_cast<const float4*>(v + (row * 4 + c) * 32);
    float t2 = b2[0];
#pragma unroll
    for (int i = 0; i < 4; ++i) {          // 4 x (16B = 8 halves)
        F4H8 U, V; U.f4 = u4[i]; V.f4 = v4[i];
#pragma unroll
        for (int jj = 0; jj < 4; ++jj) {
            float2 uf = __half22float2(U.h2[jj]);
            float2 vf = __half22float2(V.h2[jj]);
            int o = i * 8 + jj * 2;
            t2 += fast_tanh(uf.x + vf.x + b1[o])     * w2[o];
            t2 += fast_tanh(uf.y + vf.y + b1[o + 1]) * w2[o + 1];
        }
    }
    float s  = fast_tanh(t2);
    float m1 = fmaxf(s, __shfl_xor(s, 1, 4));
    float mx = fmaxf(m1, __shfl_xor(m1, 2, 4));
    float ex = __expf(s - mx);
    float sm = ex + __shfl_xor(ex, 1, 4);
    sm = sm + __shfl_xor(sm, 2, 4);
    float val = ex / sm;
    if (FINAL) {
        dst[(unsigned)eArr[idx] * 4 + c] = val;
    } else {
        eaIn[(unsigned)ent.y * 4 + c] = val;
        eaOut[(unsigned)poPA[idx] * 4 + c] = val;
    }
}

// Node net, pure-gather version: h = r[row] + nb1 + sum_in eaIn*p[prt] +
// sum_out eaOut*q[prt]; H = tanh(tanh(h) @ nW2 + nb2) -> m[row][0:32] in place.
// 8 rows x 32 lanes; padded batch-8 gathers, no conditionals in the hot loop.
__global__ void k_node(float* __restrict__ m, const float* __restrict__ rbuf,
                       const __half* __restrict__ p, const __half* __restrict__ q,
                       const float* __restrict__ eaIn, const float* __restrict__ eaOut,
                       const int* __restrict__ pinOff, const int* __restrict__ poutOff,
                       const unsigned short* __restrict__ inPrt,
                       const unsigned short* __restrict__ outPrt,
                       const float* __restrict__ nb1,
                       const float* __restrict__ nW2, const float* __restrict__ nb2) {
    __shared__ float sW2[32 * 32];
    __shared__ float tb[8 * 33];
    unsigned tid = threadIdx.x;
    for (unsigned i = tid; i < 32 * 32; i += 256) sW2[i] = nW2[i];
    unsigned rl = tid >> 5, k = tid & 31;
    unsigned row = blockIdx.x * 8 + rl;   // flat (n*4 + c)
    unsigned n = row >> 2, c = row & 3;
    float h = rbuf[(size_t)row * 32 + k] + nb1[k];

    unsigned gOff = c * 32 + k;
    {   // in-gather (padded length, multiple of 8; pad slots have prt=0, ea=0)
        int b1i = pinOff[n + 1];
        for (int b = pinOff[n]; b < b1i; b += 8) {
            unsigned prt[8]; float av[8];
#pragma unroll
            for (int i = 0; i < 8; ++i) {
                prt[i] = inPrt[b + i];
                av[i]  = eaIn[(unsigned)(b + i) * 4 + c];
            }
#pragma unroll
            for (int i = 0; i < 8; ++i)
                h += av[i] * __half2float(p[prt[i] * 128u + gOff]);
        }
    }
    {   // out-gather
        int b1o = poutOff[n + 1];
        for (int b = poutOff[n]; b < b1o; b += 8) {
            unsigned prt[8]; float av[8];
#pragma unroll
            for (int i = 0; i < 8; ++i) {
                prt[i] = outPrt[b + i];
                av[i]  = eaOut[(unsigned)(b + i) * 4 + c];
            }
#pragma unroll
            for (int i = 0; i < 8; ++i)
                h += av[i] * __half2float(q[prt[i] * 128u + gOff]);
        }
    }
    float t = fast_tanh(h);
    tb[rl * 33 + k] = t;
    __syncthreads();
    float hh = nb2[k];
#pragma unroll
    for (int kk = 0; kk < 32; ++kk) hh += tb[rl * 33 + kk] * sW2[kk * 32 + k];
    m[(size_t)row * HI + k] = fast_tanh(hh);
}

extern "C" void kernel_launch(void* const* d_in, const int* in_sizes, int n_in,
                              void* d_out, int out_size, void* d_ws, size_t ws_size,
                              hipStream_t stream) {
    const float* x   = (const float*)d_in[0];
    const int*   ei  = (const int*)d_in[1];
    const float* inW = (const float*)d_in[2];
    const float* inb = (const float*)d_in[3];
    const float* eW1 = (const float*)d_in[4];
    const float* eb1 = (const float*)d_in[5];
    const float* eW2 = (const float*)d_in[6];
    const float* eb2 = (const float*)d_in[7];
    const float* nW1 = (const float*)d_in[8];
    const float* nb1 = (const float*)d_in[9];
    const float* nW2 = (const float*)d_in[10];
    const float* nb2 = (const float*)d_in[11];
    float* out = (float*)d_out;

    // Workspace (~138 MB): m 28.8 | u,v,p,q fp16 51.2 | r fp32 25.6 |
    // eaIn/eaOut 21.5 | inL2 3.2 | poPA 1.6 | eArr 1.6 | prt u16 2.7 | offs ~1.0
    float*  m     = (float*)d_ws;
    __half* u     = (__half*)(m + (size_t)ROWS_P * HI);
    __half* v     = u + (size_t)ROWS_P * 32;
    __half* p     = v + (size_t)ROWS_P * 32;
    __half* q     = p + (size_t)ROWS_P * 32;
    float*  rbuf  = (float*)(q + (size_t)ROWS_P * 32);
    float*  eaIn  = rbuf + (size_t)ROWS_P * 32;
    float*  eaOut = eaIn + (size_t)PADCAP * 4;
    int2*   inL2  = (int2*)(eaOut + (size_t)PADCAP * 4);
    int*    poPA  = (int*)(inL2 + N_EDGES);
    int*    eArr  = poPA + N_EDGES;
    unsigned short* inPrt  = (unsigned short*)(eArr + N_EDGES);
    unsigned short* outPrt = inPrt + PADCAP;
    int*    inOffRaw = (int*)(outPrt + PADCAP);
    int*    pinOff   = inOffRaw + (N_NODES + 1);
    int*    poutOff  = pinOff + (N_NODES + 1);
    int*    inCur    = poutOff + (N_NODES + 1);
    int*    outCur   = inCur + N_NODES;

    const int gridE = (N_EDGES + 255) / 256;

    for (int j = 0; j < 3; ++j) {
        const int*   rowI = ei + (size_t)j * 2 * N_EDGES;
        const int*   colI = rowI + N_EDGES;
        const float* eW1j = eW1 + j * 72 * 32;
        const float* eb1j = eb1 + j * 32;
        const float* eW2j = eW2 + j * 32;
        const float* eb2j = eb2 + j;
        const float* nW1j = nW1 + j * 108 * 32;
        const float* nb1j = nb1 + j * 32;
        const float* nW2j = nW2 + j * 1024;
        const float* nb2j = nb2 + j * 32;

        // CSR build (padded)
        hipMemsetAsync(inCur, 0, 2 * N_NODES * sizeof(int), stream);
        k_hist<<<gridE, 256, 0, stream>>>(rowI, colI, inCur, outCur);
        k_scan<<<3, 1024, 0, stream>>>(inCur, outCur, inOffRaw, pinOff, poutOff);
        hipMemsetAsync(inCur, 0, 2 * N_NODES * sizeof(int), stream);
        hipMemsetAsync(inPrt, 0, 2 * (size_t)PADCAP * sizeof(unsigned short), stream);
        hipMemsetAsync(eaIn, 0, 2 * (size_t)PADCAP * 4 * sizeof(float), stream);
        k_fill<<<gridE, 256, 0, stream>>>(rowI, colI, inOffRaw, pinOff, poutOff,
                                          inCur, outCur, inL2, poPA, eArr, inPrt, outPrt);

        k_init<<<(N_NODES * HI + 255) / 256, 256, 0, stream>>>(
            x + (size_t)j * N_NODES * 4, inW + j * 128, inb + j * 32, m);

        for (int it = 0; it < 3; ++it) {
            k_gemm5<<<ROWS_P / 32, 320, 0, stream>>>(m, eW1j, nW1j, u, v, p, q, rbuf);
            k_edge<false><<<N_EDGES * 4 / 256, 256, 0, stream>>>(
                inL2, poPA, eArr, u, v, eb1j, eW2j, eb2j, eaIn, eaOut, nullptr);
            k_node<<<ROWS_P / 8, 256, 0, stream>>>(m, rbuf, p, q, eaIn, eaOut,
                                                   pinOff, poutOff, inPrt, outPrt,
                                                   nb1j, nW2j, nb2j);
        }
        k_gemm2<<<ROWS_P / 32, 256, 0, stream>>>(m, eW1j, eW1j + 36 * 32, u, v);
        k_edge<true><<<N_EDGES * 4 / 256, 256, 0, stream>>>(
            inL2, poPA, eArr, u, v, eb1j, eW2j, eb2j, nullptr, nullptr,
            out + (size_t)j * N_EDGES * 4);
    }
}

// Round 12
// 1911.193 us; speedup vs baseline: 1.5816x; 1.0293x over previous
//
#include <hip/hip_runtime.h>
#include <hip/hip_fp16.h>

#define N_NODES 50000
#define N_EDGES 400000
#define NCLS 4
#define HID 32
#define HI 36                        // HID + IN_DIM
#define ROWS_P (N_NODES * NCLS)      // 200000 per-plane (n,c) rows
#define PADCAP 672000                // padded list capacity (E + ~3.5*N expected, 32-sigma safe)

// tanh(x) = 1 - 2/(exp(2x)+1); clamp avoids inf*0 NaN in the NR step.
__device__ __forceinline__ float fast_tanh(float x) {
    x = fminf(15.0f, fmaxf(-15.0f, x));
    float e = __expf(2.0f * x);
    float d = 1.0f + e;
    float r = __builtin_amdgcn_rcpf(d);
    r = r * (2.0f - d * r);   // one Newton step
    return 1.0f - 2.0f * r;
}

union F4H8 { float4 f4; __half2 h2[4]; };

// Per plane: m[n][c][0:32] = tanh(x @ inW + inb), m[n][c][32:36] = x (same across c)
__global__ void k_init(const float* __restrict__ x, const float* __restrict__ W,
                       const float* __restrict__ b, float* __restrict__ m) {
    unsigned t = blockIdx.x * 256 + threadIdx.x;
    if (t >= N_NODES * HI) return;
    unsigned idx = t % HI;
    unsigned n   = t / HI;
    float x0 = x[n * 4 + 0], x1 = x[n * 4 + 1];
    float x2 = x[n * 4 + 2], x3 = x[n * 4 + 3];
    float val;
    if (idx < 32) {
        float a = b[idx];
        a += x0 * W[idx] + x1 * W[32 + idx] + x2 * W[64 + idx] + x3 * W[96 + idx];
        val = fast_tanh(a);
    } else {
        val = (idx == 32) ? x0 : (idx == 33) ? x1 : (idx == 34) ? x2 : x3;
    }
    float* dst = m + (size_t)n * (NCLS * HI) + idx;
    dst[0] = val; dst[HI] = val; dst[2 * HI] = val; dst[3 * HI] = val;
}

// ---------------- CSR build (per plane, once) ----------------
__global__ void k_hist(const int* __restrict__ rowI, const int* __restrict__ colI,
                       int* __restrict__ inCnt, int* __restrict__ outCnt) {
    unsigned e = blockIdx.x * 256 + threadIdx.x;
    if (e >= N_EDGES) return;
    atomicAdd(&inCnt[colI[e]], 1);
    atomicAdd(&outCnt[rowI[e]], 1);
}

// Exclusive scan. block 0: raw in -> inOffRaw; block 1: padded-8 in -> pinOff;
// block 2: padded-8 out -> poutOff.
__global__ void k_scan(const int* __restrict__ inCnt, const int* __restrict__ outCnt,
                       int* __restrict__ inOffRaw, int* __restrict__ pinOff,
                       int* __restrict__ poutOff) {
    const int* cnt = (blockIdx.x == 2) ? outCnt : inCnt;
    int* off = (blockIdx.x == 0) ? inOffRaw : (blockIdx.x == 1) ? pinOff : poutOff;
    bool pad = blockIdx.x != 0;
    __shared__ int sh[16];
    __shared__ int carry;
    int tid = threadIdx.x;            // 1024
    int lane = tid & 63, wid = tid >> 6;
    if (tid == 0) carry = 0;
    __syncthreads();
    for (int base = 0; base < N_NODES; base += 1024) {
        int i = base + tid;
        int v = (i < N_NODES) ? cnt[i] : 0;
        if (pad) v = (v + 7) & ~7;
        int val = v;
#pragma unroll
        for (int d = 1; d < 64; d <<= 1) {
            int t = __shfl_up(val, d, 64);
            if (lane >= d) val += t;
        }
        if (lane == 63) sh[wid] = val;
        __syncthreads();
        if (tid < 16) {
            int s = sh[tid];
#pragma unroll
            for (int d = 1; d < 16; d <<= 1) {
                int t = __shfl_up(s, d, 16);
                if (tid >= d) s += t;
            }
            sh[tid] = s;
        }
        __syncthreads();
        int waveOff = (wid == 0) ? 0 : sh[wid - 1];
        int incl = val + waveOff + carry;
        if (i < N_NODES) off[i] = incl - v;
        __syncthreads();
        if (tid == 1023) carry = incl;
        __syncthreads();
    }
    if (tid == 0) off[N_NODES] = carry;
}

// Dense in-CSR entry for k_edge: inL2[dense]=(row|col<<16, piP), poPA[dense]=poP,
// eArr[dense]=e. Padded gather arrays: inPrt[piP]=row, outPrt[poP]=col
// (pad slots stay 0 from the per-plane memset).
__global__ void k_fill(const int* __restrict__ rowI, const int* __restrict__ colI,
                       const int* __restrict__ inOffRaw, const int* __restrict__ pinOff,
                       const int* __restrict__ poutOff,
                       int* __restrict__ inCur, int* __restrict__ outCur,
                       int2* __restrict__ inL2, int* __restrict__ poPA,
                       int* __restrict__ eArr,
                       unsigned short* __restrict__ inPrt,
                       unsigned short* __restrict__ outPrt) {
    unsigned e = blockIdx.x * 256 + threadIdx.x;
    if (e >= N_EDGES) return;
    int r = rowI[e], cn = colI[e];
    int liIn  = atomicAdd(&inCur[cn], 1);
    int liOut = atomicAdd(&outCur[r], 1);
    int dense = inOffRaw[cn] + liIn;
    int piP   = pinOff[cn] + liIn;
    int poP   = poutOff[r] + liOut;
    inL2[dense] = make_int2(r | (cn << 16), piP);
    poPA[dense] = poP;
    eArr[dense] = (int)e;
    inPrt[piP]  = (unsigned short)r;
    outPrt[poP] = (unsigned short)cn;
}

// ---------------- per-iteration kernels ----------------

// Fused 5-plane LDS-staged GEMM (320 threads): block stages 32 contiguous m-rows
// into LDS, each thread owns one of 160 output cols (u|v|p|q fp16, r fp32) with
// wcol[36] register-resident; 2 row-groups x 16 rows.
__global__ void k_gemm5(const float* __restrict__ m,
                        const float* __restrict__ eW1, const float* __restrict__ nW1,
                        __half* __restrict__ u, __half* __restrict__ v,
                        __half* __restrict__ p, __half* __restrict__ q,
                        float* __restrict__ r) {
    constexpr int RPB = 32;
    __shared__ float sm[RPB * HI];        // 4.6 KB
    unsigned tid = threadIdx.x;           // 320
    unsigned r0  = blockIdx.x * RPB;
    {
        const float4* gsrc = reinterpret_cast<const float4*>(m + (size_t)r0 * HI);
        float4* ldst = reinterpret_cast<float4*>(sm);
        for (unsigned i = tid; i < RPB * HI / 4; i += 320) ldst[i] = gsrc[i];
    }
    unsigned o = tid % 160, grp = tid / 160;   // grp in {0,1}
    unsigned sub = o >> 5, oo = o & 31;
    const float* W = (sub == 0) ? eW1 : (sub == 1) ? eW1 + 36 * 32 :
                     (sub == 2) ? nW1 : (sub == 3) ? nW1 + 36 * 32 : nW1 + 72 * 32;
    __half* dsth   = (sub == 0) ? u : (sub == 1) ? v : (sub == 2) ? p : q;
    float wcol[36];
#pragma unroll
    for (int k = 0; k < 36; ++k) wcol[k] = W[k * 32 + oo];
    __syncthreads();
#pragma unroll
    for (int i = 0; i < 16; ++i) {
        unsigned rloc = grp * 16 + i;
        const float4* mv4 = reinterpret_cast<const float4*>(sm + rloc * HI);
        float acc = 0.f;
#pragma unroll
        for (int t = 0; t < 9; ++t) {
            float4 mv = mv4[t];
            acc += mv.x * wcol[4 * t + 0];
            acc += mv.y * wcol[4 * t + 1];
            acc += mv.z * wcol[4 * t + 2];
            acc += mv.w * wcol[4 * t + 3];
        }
        size_t off = (size_t)(r0 + rloc) * 32 + oo;
        if (sub == 4) r[off] = acc;
        else          dsth[off] = __float2half_rn(acc);
    }
}

// Final-pass projection: u|v only (LDS-staged, 256 threads).
__global__ void k_gemm2(const float* __restrict__ m, const float* __restrict__ W0,
                        const float* __restrict__ W1,
                        __half* __restrict__ o0, __half* __restrict__ o1) {
    constexpr int RPB = 32;
    __shared__ float sm[RPB * HI];
    unsigned tid = threadIdx.x;
    unsigned r0  = blockIdx.x * RPB;
    {
        const float4* gsrc = reinterpret_cast<const float4*>(m + (size_t)r0 * HI);
        float4* ldst = reinterpret_cast<float4*>(sm);
        for (unsigned i = tid; i < RPB * HI / 4; i += 256) ldst[i] = gsrc[i];
    }
    unsigned o = tid % 64, grp = tid / 64;     // 4 row-groups of 8
    unsigned sub = o >> 5, oo = o & 31;
    const float* W = sub ? W1 : W0;
    __half* dst    = sub ? o1 : o0;
    float wcol[36];
#pragma unroll
    for (int k = 0; k < 36; ++k) wcol[k] = W[k * 32 + oo];
    __syncthreads();
#pragma unroll
    for (int i = 0; i < 8; ++i) {
        unsigned rloc = grp * 8 + i;
        const float4* mv4 = reinterpret_cast<const float4*>(sm + rloc * HI);
        float acc = 0.f;
#pragma unroll
        for (int t = 0; t < 9; ++t) {
            float4 mv = mv4[t];
            acc += mv.x * wcol[4 * t + 0];
            acc += mv.y * wcol[4 * t + 1];
            acc += mv.z * wcol[4 * t + 2];
            acc += mv.w * wcol[4 * t + 3];
        }
        dst[(size_t)(r0 + rloc) * 32 + oo] = __float2half_rn(acc);
    }
}

// Edges in in-CSR order (grouped by col -> u side L1-resident).
// Per (idx,c): s = tanh(sum_o tanh(u[col]+v[row]+b1)*w2 + b2); softmax over c (4 lanes).
template <bool FINAL>
__global__ void k_edge(const int2* __restrict__ inL2, const int* __restrict__ poPA,
                       const int* __restrict__ eArr,
                       const __half* __restrict__ u, const __half* __restrict__ v,
                       const float* __restrict__ b1, const float* __restrict__ w2,
                       const float* __restrict__ b2,
                       float* __restrict__ eaIn, float* __restrict__ eaOut,
                       float* __restrict__ dst) {
    unsigned g   = blockIdx.x * 256 + threadIdx.x;   // exact grid: E*4
    unsigned c   = g & 3;
    unsigned idx = g >> 2;
    int2 ent = inL2[idx];
    unsigned rc  = (unsigned)ent.x;
    unsigned row = rc & 0xFFFFu, col = rc >> 16;
    const float4* u4 = reinterpret_cast<const float4*>(u + (col * 4 + c) * 32);
    const float4* v4 = reinterpret_cast<const float4*>(v + (row * 4 + c) * 32);
    float t2 = b2[0];
#pragma unroll
    for (int i = 0; i < 4; ++i) {          // 4 x (16B = 8 halves)
        F4H8 U, V; U.f4 = u4[i]; V.f4 = v4[i];
#pragma unroll
        for (int jj = 0; jj < 4; ++jj) {
            float2 uf = __half22float2(U.h2[jj]);
            float2 vf = __half22float2(V.h2[jj]);
            int o = i * 8 + jj * 2;
            t2 += fast_tanh(uf.x + vf.x + b1[o])     * w2[o];
            t2 += fast_tanh(uf.y + vf.y + b1[o + 1]) * w2[o + 1];
        }
    }
    float s  = fast_tanh(t2);
    float m1 = fmaxf(s, __shfl_xor(s, 1, 4));
    float mx = fmaxf(m1, __shfl_xor(m1, 2, 4));
    float ex = __expf(s - mx);
    float sm = ex + __shfl_xor(ex, 1, 4);
    sm = sm + __shfl_xor(sm, 2, 4);
    float val = ex / sm;
    if (FINAL) {
        dst[(unsigned)eArr[idx] * 4 + c] = val;
    } else {
        eaIn[(unsigned)ent.y * 4 + c] = val;
        eaOut[(unsigned)poPA[idx] * 4 + c] = val;
    }
}

// Node net, wave-per-node: lane = (c2,k) handles classes c2 and c2+2.
// Per visit the wave issues 1 prt load, 2 ea loads, 2x128B gathers.
// Epilogue exchanges t via __shfl (no block-level barrier after the loops).
__global__ void k_node(float* __restrict__ m, const float* __restrict__ rbuf,
                       const __half* __restrict__ p, const __half* __restrict__ q,
                       const float* __restrict__ eaIn, const float* __restrict__ eaOut,
                       const int* __restrict__ pinOff, const int* __restrict__ poutOff,
                       const unsigned short* __restrict__ inPrt,
                       const unsigned short* __restrict__ outPrt,
                       const float* __restrict__ nb1,
                       const float* __restrict__ nW2, const float* __restrict__ nb2) {
    __shared__ float sW2[32 * 32];
    unsigned tid = threadIdx.x;
    for (unsigned i = tid; i < 32 * 32; i += 256) sW2[i] = nW2[i];
    unsigned wv   = tid >> 6;            // wave 0..3 -> node
    unsigned lane = tid & 63;
    unsigned c2 = lane >> 5, k = lane & 31;
    unsigned n = blockIdx.x * 4 + wv;
    float b1k = nb1[k];
    float h0 = rbuf[((size_t)n * 4 + c2) * 32 + k] + b1k;        // class c2
    float h1 = rbuf[((size_t)n * 4 + c2 + 2) * 32 + k] + b1k;    // class c2+2
    unsigned gOff0 = c2 * 32 + k;
    unsigned gOff1 = gOff0 + 64;
    __syncthreads();   // sW2 staged (before any variable-length work)
    {   // in-gather (padded length, multiple of 8; pad slots have prt=0, ea=0)
        int b1i = pinOff[n + 1];
        for (int b = pinOff[n]; b < b1i; b += 8) {
            unsigned prt[8]; float a0[8], a1[8];
#pragma unroll
            for (int i = 0; i < 8; ++i) {
                prt[i] = inPrt[b + i];
                a0[i]  = eaIn[(unsigned)(b + i) * 4 + c2];
                a1[i]  = eaIn[(unsigned)(b + i) * 4 + c2 + 2];
            }
#pragma unroll
            for (int i = 0; i < 8; ++i) {
                h0 += a0[i] * __half2float(p[prt[i] * 128u + gOff0]);
                h1 += a1[i] * __half2float(p[prt[i] * 128u + gOff1]);
            }
        }
    }
    {   // out-gather
        int b1o = poutOff[n + 1];
        for (int b = poutOff[n]; b < b1o; b += 8) {
            unsigned prt[8]; float a0[8], a1[8];
#pragma unroll
            for (int i = 0; i < 8; ++i) {
                prt[i] = outPrt[b + i];
                a0[i]  = eaOut[(unsigned)(b + i) * 4 + c2];
                a1[i]  = eaOut[(unsigned)(b + i) * 4 + c2 + 2];
            }
#pragma unroll
            for (int i = 0; i < 8; ++i) {
                h0 += a0[i] * __half2float(q[prt[i] * 128u + gOff0]);
                h1 += a1[i] * __half2float(q[prt[i] * 128u + gOff1]);
            }
        }
    }
    float t0 = fast_tanh(h0);   // class c2, dim k (lane-local)
    float t1 = fast_tanh(h1);   // class c2+2, dim k
    float hh0 = nb2[k], hh1 = hh0;
#pragma unroll
    for (int kk = 0; kk < 32; ++kk) {
        float w = sW2[kk * 32 + k];
        float s0 = __shfl(t0, (int)(c2 * 32 + kk), 64);   // t(class c2, kk)
        float s1 = __shfl(t1, (int)(c2 * 32 + kk), 64);   // t(class c2+2, kk)
        hh0 += s0 * w;
        hh1 += s1 * w;
    }
    m[((size_t)n * 4 + c2) * HI + k]     = fast_tanh(hh0);
    m[((size_t)n * 4 + c2 + 2) * HI + k] = fast_tanh(hh1);
}

extern "C" void kernel_launch(void* const* d_in, const int* in_sizes, int n_in,
                              void* d_out, int out_size, void* d_ws, size_t ws_size,
                              hipStream_t stream) {
    const float* x   = (const float*)d_in[0];
    const int*   ei  = (const int*)d_in[1];
    const float* inW = (const float*)d_in[2];
    const float* inb = (const float*)d_in[3];
    const float* eW1 = (const float*)d_in[4];
    const float* eb1 = (const float*)d_in[5];
    const float* eW2 = (const float*)d_in[6];
    const float* eb2 = (const float*)d_in[7];
    const float* nW1 = (const float*)d_in[8];
    const float* nb1 = (const float*)d_in[9];
    const float* nW2 = (const float*)d_in[10];
    const float* nb2 = (const float*)d_in[11];
    float* out = (float*)d_out;

    // Workspace (~138 MB): m 28.8 | u,v,p,q fp16 51.2 | r fp32 25.6 |
    // eaIn/eaOut 21.5 | inL2 3.2 | poPA 1.6 | eArr 1.6 | prt u16 2.7 | offs ~1.0
    float*  m     = (float*)d_ws;
    __half* u     = (__half*)(m + (size_t)ROWS_P * HI);
    __half* v     = u + (size_t)ROWS_P * 32;
    __half* p     = v + (size_t)ROWS_P * 32;
    __half* q     = p + (size_t)ROWS_P * 32;
    float*  rbuf  = (float*)(q + (size_t)ROWS_P * 32);
    float*  eaIn  = rbuf + (size_t)ROWS_P * 32;
    float*  eaOut = eaIn + (size_t)PADCAP * 4;
    int2*   inL2  = (int2*)(eaOut + (size_t)PADCAP * 4);
    int*    poPA  = (int*)(inL2 + N_EDGES);
    int*    eArr  = poPA + N_EDGES;
    unsigned short* inPrt  = (unsigned short*)(eArr + N_EDGES);
    unsigned short* outPrt = inPrt + PADCAP;
    int*    inOffRaw = (int*)(outPrt + PADCAP);
    int*    pinOff   = inOffRaw + (N_NODES + 1);
    int*    poutOff  = pinOff + (N_NODES + 1);
    int*    inCur    = poutOff + (N_NODES + 1);
    int*    outCur   = inCur + N_NODES;

    const int gridE = (N_EDGES + 255) / 256;

    for (int j = 0; j < 3; ++j) {
        const int*   rowI = ei + (size_t)j * 2 * N_EDGES;
        const int*   colI = rowI + N_EDGES;
        const float* eW1j = eW1 + j * 72 * 32;
        const float* eb1j = eb1 + j * 32;
        const float* eW2j = eW2 + j * 32;
        const float* eb2j = eb2 + j;
        const float* nW1j = nW1 + j * 108 * 32;
        const float* nb1j = nb1 + j * 32;
        const float* nW2j = nW2 + j * 1024;
        const float* nb2j = nb2 + j * 32;

        // CSR build (padded)
        hipMemsetAsync(inCur, 0, 2 * N_NODES * sizeof(int), stream);
        k_hist<<<gridE, 256, 0, stream>>>(rowI, colI, inCur, outCur);
        k_scan<<<3, 1024, 0, stream>>>(inCur, outCur, inOffRaw, pinOff, poutOff);
        hipMemsetAsync(inCur, 0, 2 * N_NODES * sizeof(int), stream);
        hipMemsetAsync(inPrt, 0, 2 * (size_t)PADCAP * sizeof(unsigned short), stream);
        hipMemsetAsync(eaIn, 0, 2 * (size_t)PADCAP * 4 * sizeof(float), stream);
        k_fill<<<gridE, 256, 0, stream>>>(rowI, colI, inOffRaw, pinOff, poutOff,
                                          inCur, outCur, inL2, poPA, eArr, inPrt, outPrt);

        k_init<<<(N_NODES * HI + 255) / 256, 256, 0, stream>>>(
            x + (size_t)j * N_NODES * 4, inW + j * 128, inb + j * 32, m);

        for (int it = 0; it < 3; ++it) {
            k_gemm5<<<ROWS_P / 32, 320, 0, stream>>>(m, eW1j, nW1j, u, v, p, q, rbuf);
            k_edge<false><<<N_EDGES * 4 / 256, 256, 0, stream>>>(
                inL2, poPA, eArr, u, v, eb1j, eW2j, eb2j, eaIn, eaOut, nullptr);
            k_node<<<N_NODES / 4, 256, 0, stream>>>(m, rbuf, p, q, eaIn, eaOut,
                                                    pinOff, poutOff, inPrt, outPrt,
                                                    nb1j, nW2j, nb2j);
        }
        k_gemm2<<<ROWS_P / 32, 256, 0, stream>>>(m, eW1j, eW1j + 36 * 32, u, v);
        k_edge<true><<<N_EDGES * 4 / 256, 256, 0, stream>>>(
            inL2, poPA, eArr, u, v, eb1j, eW2j, eb2j, nullptr, nullptr,
            out + (size_t)j * N_EDGES * 4);
    }
}

// Round 13
// 1863.851 us; speedup vs baseline: 1.6218x; 1.0254x over previous
//
#include <hip/hip_runtime.h>
#include <hip/hip_fp16.h>

#define N_NODES 50000
#define N_EDGES 400000
#define NCLS 4
#define HID 32
#define HI 36                        // HID + IN_DIM
#define ROWS_P (N_NODES * NCLS)      // 200000 per-plane (n,c) rows
#define PADCAP 672000                // padded list capacity (E + ~3.5*N expected, 32-sigma safe)

// tanh(x) = 1 - 2/(exp(2x)+1); clamp avoids inf*0 NaN in the NR step.
__device__ __forceinline__ float fast_tanh(float x) {
    x = fminf(15.0f, fmaxf(-15.0f, x));
    float e = __expf(2.0f * x);
    float d = 1.0f + e;
    float r = __builtin_amdgcn_rcpf(d);
    r = r * (2.0f - d * r);   // one Newton step
    return 1.0f - 2.0f * r;
}

union F4H8 { float4 f4; __half2 h2[4]; };

// Per plane: m[n][c][0:32] = tanh(x @ inW + inb), m[n][c][32:36] = x (same across c)
__global__ void k_init(const float* __restrict__ x, const float* __restrict__ W,
                       const float* __restrict__ b, float* __restrict__ m) {
    unsigned t = blockIdx.x * 256 + threadIdx.x;
    if (t >= N_NODES * HI) return;
    unsigned idx = t % HI;
    unsigned n   = t / HI;
    float x0 = x[n * 4 + 0], x1 = x[n * 4 + 1];
    float x2 = x[n * 4 + 2], x3 = x[n * 4 + 3];
    float val;
    if (idx < 32) {
        float a = b[idx];
        a += x0 * W[idx] + x1 * W[32 + idx] + x2 * W[64 + idx] + x3 * W[96 + idx];
        val = fast_tanh(a);
    } else {
        val = (idx == 32) ? x0 : (idx == 33) ? x1 : (idx == 34) ? x2 : x3;
    }
    float* dst = m + (size_t)n * (NCLS * HI) + idx;
    dst[0] = val; dst[HI] = val; dst[2 * HI] = val; dst[3 * HI] = val;
}

// ---------------- CSR build (per plane, once) ----------------
__global__ void k_hist(const int* __restrict__ rowI, const int* __restrict__ colI,
                       int* __restrict__ inCnt, int* __restrict__ outCnt) {
    unsigned e = blockIdx.x * 256 + threadIdx.x;
    if (e >= N_EDGES) return;
    atomicAdd(&inCnt[colI[e]], 1);
    atomicAdd(&outCnt[rowI[e]], 1);
}

// Exclusive scan. block 0: raw in -> inOffRaw; block 1: padded-8 in -> pinOff;
// block 2: padded-8 out -> poutOff.
__global__ void k_scan(const int* __restrict__ inCnt, const int* __restrict__ outCnt,
                       int* __restrict__ inOffRaw, int* __restrict__ pinOff,
                       int* __restrict__ poutOff) {
    const int* cnt = (blockIdx.x == 2) ? outCnt : inCnt;
    int* off = (blockIdx.x == 0) ? inOffRaw : (blockIdx.x == 1) ? pinOff : poutOff;
    bool pad = blockIdx.x != 0;
    __shared__ int sh[16];
    __shared__ int carry;
    int tid = threadIdx.x;            // 1024
    int lane = tid & 63, wid = tid >> 6;
    if (tid == 0) carry = 0;
    __syncthreads();
    for (int base = 0; base < N_NODES; base += 1024) {
        int i = base + tid;
        int v = (i < N_NODES) ? cnt[i] : 0;
        if (pad) v = (v + 7) & ~7;
        int val = v;
#pragma unroll
        for (int d = 1; d < 64; d <<= 1) {
            int t = __shfl_up(val, d, 64);
            if (lane >= d) val += t;
        }
        if (lane == 63) sh[wid] = val;
        __syncthreads();
        if (tid < 16) {
            int s = sh[tid];
#pragma unroll
            for (int d = 1; d < 16; d <<= 1) {
                int t = __shfl_up(s, d, 16);
                if (tid >= d) s += t;
            }
            sh[tid] = s;
        }
        __syncthreads();
        int waveOff = (wid == 0) ? 0 : sh[wid - 1];
        int incl = val + waveOff + carry;
        if (i < N_NODES) off[i] = incl - v;
        __syncthreads();
        if (tid == 1023) carry = incl;
        __syncthreads();
    }
    if (tid == 0) off[N_NODES] = carry;
}

// Dense in-CSR entry for k_edge: inL2[dense]=(row|col<<16, piP), poPA[dense]=poP,
// eArr[dense]=e. Padded gather arrays: inPrt[piP]=row, outPrt[poP]=col
// (pad slots stay 0 from the per-plane memset).
__global__ void k_fill(const int* __restrict__ rowI, const int* __restrict__ colI,
                       const int* __restrict__ inOffRaw, const int* __restrict__ pinOff,
                       const int* __restrict__ poutOff,
                       int* __restrict__ inCur, int* __restrict__ outCur,
                       int2* __restrict__ inL2, int* __restrict__ poPA,
                       int* __restrict__ eArr,
                       unsigned short* __restrict__ inPrt,
                       unsigned short* __restrict__ outPrt) {
    unsigned e = blockIdx.x * 256 + threadIdx.x;
    if (e >= N_EDGES) return;
    int r = rowI[e], cn = colI[e];
    int liIn  = atomicAdd(&inCur[cn], 1);
    int liOut = atomicAdd(&outCur[r], 1);
    int dense = inOffRaw[cn] + liIn;
    int piP   = pinOff[cn] + liIn;
    int poP   = poutOff[r] + liOut;
    inL2[dense] = make_int2(r | (cn << 16), piP);
    poPA[dense] = poP;
    eArr[dense] = (int)e;
    inPrt[piP]  = (unsigned short)r;
    outPrt[poP] = (unsigned short)cn;
}

// ---------------- per-iteration kernels ----------------

// Fused 5-plane LDS-staged GEMM (320 threads): block stages 32 contiguous m-rows
// into LDS, each thread owns one of 160 output cols (u|v|p|q|r, all fp16) with
// wcol[36] register-resident; 2 row-groups x 16 rows.
__global__ void k_gemm5(const float* __restrict__ m,
                        const float* __restrict__ eW1, const float* __restrict__ nW1,
                        __half* __restrict__ u, __half* __restrict__ v,
                        __half* __restrict__ p, __half* __restrict__ q,
                        __half* __restrict__ r) {
    constexpr int RPB = 32;
    __shared__ float sm[RPB * HI];        // 4.6 KB
    unsigned tid = threadIdx.x;           // 320
    unsigned r0  = blockIdx.x * RPB;
    {
        const float4* gsrc = reinterpret_cast<const float4*>(m + (size_t)r0 * HI);
        float4* ldst = reinterpret_cast<float4*>(sm);
        for (unsigned i = tid; i < RPB * HI / 4; i += 320) ldst[i] = gsrc[i];
    }
    unsigned o = tid % 160, grp = tid / 160;   // grp in {0,1}
    unsigned sub = o >> 5, oo = o & 31;
    const float* W = (sub == 0) ? eW1 : (sub == 1) ? eW1 + 36 * 32 :
                     (sub == 2) ? nW1 : (sub == 3) ? nW1 + 36 * 32 : nW1 + 72 * 32;
    __half* dsth   = (sub == 0) ? u : (sub == 1) ? v : (sub == 2) ? p :
                     (sub == 3) ? q : r;
    float wcol[36];
#pragma unroll
    for (int k = 0; k < 36; ++k) wcol[k] = W[k * 32 + oo];
    __syncthreads();
#pragma unroll
    for (int i = 0; i < 16; ++i) {
        unsigned rloc = grp * 16 + i;
        const float4* mv4 = reinterpret_cast<const float4*>(sm + rloc * HI);
        float acc = 0.f;
#pragma unroll
        for (int t = 0; t < 9; ++t) {
            float4 mv = mv4[t];
            acc += mv.x * wcol[4 * t + 0];
            acc += mv.y * wcol[4 * t + 1];
            acc += mv.z * wcol[4 * t + 2];
            acc += mv.w * wcol[4 * t + 3];
        }
        dsth[(size_t)(r0 + rloc) * 32 + oo] = __float2half_rn(acc);
    }
}

// Final-pass projection: u|v only (LDS-staged, 256 threads).
__global__ void k_gemm2(const float* __restrict__ m, const float* __restrict__ W0,
                        const float* __restrict__ W1,
                        __half* __restrict__ o0, __half* __restrict__ o1) {
    constexpr int RPB = 32;
    __shared__ float sm[RPB * HI];
    unsigned tid = threadIdx.x;
    unsigned r0  = blockIdx.x * RPB;
    {
        const float4* gsrc = reinterpret_cast<const float4*>(m + (size_t)r0 * HI);
        float4* ldst = reinterpret_cast<float4*>(sm);
        for (unsigned i = tid; i < RPB * HI / 4; i += 256) ldst[i] = gsrc[i];
    }
    unsigned o = tid % 64, grp = tid / 64;     // 4 row-groups of 8
    unsigned sub = o >> 5, oo = o & 31;
    const float* W = sub ? W1 : W0;
    __half* dst    = sub ? o1 : o0;
    float wcol[36];
#pragma unroll
    for (int k = 0; k < 36; ++k) wcol[k] = W[k * 32 + oo];
    __syncthreads();
#pragma unroll
    for (int i = 0; i < 8; ++i) {
        unsigned rloc = grp * 8 + i;
        const float4* mv4 = reinterpret_cast<const float4*>(sm + rloc * HI);
        float acc = 0.f;
#pragma unroll
        for (int t = 0; t < 9; ++t) {
            float4 mv = mv4[t];
            acc += mv.x * wcol[4 * t + 0];
            acc += mv.y * wcol[4 * t + 1];
            acc += mv.z * wcol[4 * t + 2];
            acc += mv.w * wcol[4 * t + 3];
        }
        dst[(size_t)(r0 + rloc) * 32 + oo] = __float2half_rn(acc);
    }
}

// Edges in in-CSR order (grouped by col -> u side L1-resident).
// Per (idx,c): s = tanh(sum_o tanh(u[col]+v[row]+b1)*w2 + b2); softmax over c (4 lanes).
template <bool FINAL>
__global__ void k_edge(const int2* __restrict__ inL2, const int* __restrict__ poPA,
                       const int* __restrict__ eArr,
                       const __half* __restrict__ u, const __half* __restrict__ v,
                       const float* __restrict__ b1, const float* __restrict__ w2,
                       const float* __restrict__ b2,
                       __half* __restrict__ eaIn, __half* __restrict__ eaOut,
                       float* __restrict__ dst) {
    unsigned g   = blockIdx.x * 256 + threadIdx.x;   // exact grid: E*4
    unsigned c   = g & 3;
    unsigned idx = g >> 2;
    int2 ent = inL2[idx];
    unsigned rc  = (unsigned)ent.x;
    unsigned row = rc & 0xFFFFu, col = rc >> 16;
    const float4* u4 = reinterpret_cast<const float4*>(u + (col * 4 + c) * 32);
    const float4* v4 = reinterpret_cast<const float4*>(v + (row * 4 + c) * 32);
    float t2 = b2[0];
#pragma unroll
    for (int i = 0; i < 4; ++i) {          // 4 x (16B = 8 halves)
        F4H8 U, V; U.f4 = u4[i]; V.f4 = v4[i];
#pragma unroll
        for (int jj = 0; jj < 4; ++jj) {
            float2 uf = __half22float2(U.h2[jj]);
            float2 vf = __half22float2(V.h2[jj]);
            int o = i * 8 + jj * 2;
            t2 += fast_tanh(uf.x + vf.x + b1[o])     * w2[o];
            t2 += fast_tanh(uf.y + vf.y + b1[o + 1]) * w2[o + 1];
        }
    }
    float s  = fast_tanh(t2);
    float m1 = fmaxf(s, __shfl_xor(s, 1, 4));
    float mx = fmaxf(m1, __shfl_xor(m1, 2, 4));
    float ex = __expf(s - mx);
    float sm = ex + __shfl_xor(ex, 1, 4);
    sm = sm + __shfl_xor(sm, 2, 4);
    float val = ex / sm;
    if (FINAL) {
        dst[(unsigned)eArr[idx] * 4 + c] = val;
    } else {
        __half hv = __float2half_rn(val);
        eaIn[(unsigned)ent.y * 4 + c] = hv;
        eaOut[(unsigned)poPA[idx] * 4 + c] = hv;
    }
}

// Node net, wave-per-node: lane = (c2,k) handles classes c2 and c2+2.
// Per visit the wave issues 1 prt load, 2 ea loads, 2x128B gathers.
// Epilogue exchanges t via __shfl (no block-level barrier after the loops).
__global__ void k_node(float* __restrict__ m, const __half* __restrict__ rbuf,
                       const __half* __restrict__ p, const __half* __restrict__ q,
                       const __half* __restrict__ eaIn, const __half* __restrict__ eaOut,
                       const int* __restrict__ pinOff, const int* __restrict__ poutOff,
                       const unsigned short* __restrict__ inPrt,
                       const unsigned short* __restrict__ outPrt,
                       const float* __restrict__ nb1,
                       const float* __restrict__ nW2, const float* __restrict__ nb2) {
    __shared__ float sW2[32 * 32];
    unsigned tid = threadIdx.x;
    for (unsigned i = tid; i < 32 * 32; i += 256) sW2[i] = nW2[i];
    unsigned wv   = tid >> 6;            // wave 0..3 -> node
    unsigned lane = tid & 63;
    unsigned c2 = lane >> 5, k = lane & 31;
    unsigned n = blockIdx.x * 4 + wv;
    float b1k = nb1[k];
    float h0 = __half2float(rbuf[((size_t)n * 4 + c2) * 32 + k]) + b1k;      // class c2
    float h1 = __half2float(rbuf[((size_t)n * 4 + c2 + 2) * 32 + k]) + b1k;  // class c2+2
    unsigned gOff0 = c2 * 32 + k;
    unsigned gOff1 = gOff0 + 64;
    __syncthreads();   // sW2 staged (before any variable-length work)
    {   // in-gather (padded length, multiple of 8; pad slots have prt=0, ea=0)
        int b1i = pinOff[n + 1];
        for (int b = pinOff[n]; b < b1i; b += 8) {
            unsigned prt[8]; float a0[8], a1[8];
#pragma unroll
            for (int i = 0; i < 8; ++i) {
                prt[i] = inPrt[b + i];
                a0[i]  = __half2float(eaIn[(unsigned)(b + i) * 4 + c2]);
                a1[i]  = __half2float(eaIn[(unsigned)(b + i) * 4 + c2 + 2]);
            }
#pragma unroll
            for (int i = 0; i < 8; ++i) {
                h0 += a0[i] * __half2float(p[prt[i] * 128u + gOff0]);
                h1 += a1[i] * __half2float(p[prt[i] * 128u + gOff1]);
            }
        }
    }
    {   // out-gather
        int b1o = poutOff[n + 1];
        for (int b = poutOff[n]; b < b1o; b += 8) {
            unsigned prt[8]; float a0[8], a1[8];
#pragma unroll
            for (int i = 0; i < 8; ++i) {
                prt[i] = outPrt[b + i];
                a0[i]  = __half2float(eaOut[(unsigned)(b + i) * 4 + c2]);
                a1[i]  = __half2float(eaOut[(unsigned)(b + i) * 4 + c2 + 2]);
            }
#pragma unroll
            for (int i = 0; i < 8; ++i) {
                h0 += a0[i] * __half2float(q[prt[i] * 128u + gOff0]);
                h1 += a1[i] * __half2float(q[prt[i] * 128u + gOff1]);
            }
        }
    }
    float t0 = fast_tanh(h0);   // class c2, dim k (lane-local)
    float t1 = fast_tanh(h1);   // class c2+2, dim k
    float hh0 = nb2[k], hh1 = hh0;
#pragma unroll
    for (int kk = 0; kk < 32; ++kk) {
        float w = sW2[kk * 32 + k];
        float s0 = __shfl(t0, (int)(c2 * 32 + kk), 64);   // t(class c2, kk)
        float s1 = __shfl(t1, (int)(c2 * 32 + kk), 64);   // t(class c2+2, kk)
        hh0 += s0 * w;
        hh1 += s1 * w;
    }
    m[((size_t)n * 4 + c2) * HI + k]     = fast_tanh(hh0);
    m[((size_t)n * 4 + c2 + 2) * HI + k] = fast_tanh(hh1);
}

extern "C" void kernel_launch(void* const* d_in, const int* in_sizes, int n_in,
                              void* d_out, int out_size, void* d_ws, size_t ws_size,
                              hipStream_t stream) {
    const float* x   = (const float*)d_in[0];
    const int*   ei  = (const int*)d_in[1];
    const float* inW = (const float*)d_in[2];
    const float* inb = (const float*)d_in[3];
    const float* eW1 = (const float*)d_in[4];
    const float* eb1 = (const float*)d_in[5];
    const float* eW2 = (const float*)d_in[6];
    const float* eb2 = (const float*)d_in[7];
    const float* nW1 = (const float*)d_in[8];
    const float* nb1 = (const float*)d_in[9];
    const float* nW2 = (const float*)d_in[10];
    const float* nb2 = (const float*)d_in[11];
    float* out = (float*)d_out;

    // Workspace (~110 MB): m 28.8 | u,v,p,q fp16 51.2 | r fp16 12.8 |
    // eaIn/eaOut fp16 10.8 | inL2 3.2 | poPA 1.6 | eArr 1.6 | prt u16 2.7 | offs ~1.0
    float*  m     = (float*)d_ws;
    __half* u     = (__half*)(m + (size_t)ROWS_P * HI);
    __half* v     = u + (size_t)ROWS_P * 32;
    __half* p     = v + (size_t)ROWS_P * 32;
    __half* q     = p + (size_t)ROWS_P * 32;
    __half* rbuf  = q + (size_t)ROWS_P * 32;
    __half* eaIn  = rbuf + (size_t)ROWS_P * 32;
    __half* eaOut = eaIn + (size_t)PADCAP * 4;
    int2*   inL2  = (int2*)(eaOut + (size_t)PADCAP * 4);
    int*    poPA  = (int*)(inL2 + N_EDGES);
    int*    eArr  = poPA + N_EDGES;
    unsigned short* inPrt  = (unsigned short*)(eArr + N_EDGES);
    unsigned short* outPrt = inPrt + PADCAP;
    int*    inOffRaw = (int*)(outPrt + PADCAP);
    int*    pinOff   = inOffRaw + (N_NODES + 1);
    int*    poutOff  = pinOff + (N_NODES + 1);
    int*    inCur    = poutOff + (N_NODES + 1);
    int*    outCur   = inCur + N_NODES;

    const int gridE = (N_EDGES + 255) / 256;

    for (int j = 0; j < 3; ++j) {
        const int*   rowI = ei + (size_t)j * 2 * N_EDGES;
        const int*   colI = rowI + N_EDGES;
        const float* eW1j = eW1 + j * 72 * 32;
        const float* eb1j = eb1 + j * 32;
        const float* eW2j = eW2 + j * 32;
        const float* eb2j = eb2 + j;
        const float* nW1j = nW1 + j * 108 * 32;
        const float* nb1j = nb1 + j * 32;
        const float* nW2j = nW2 + j * 1024;
        const float* nb2j = nb2 + j * 32;

        // CSR build (padded)
        hipMemsetAsync(inCur, 0, 2 * N_NODES * sizeof(int), stream);
        k_hist<<<gridE, 256, 0, stream>>>(rowI, colI, inCur, outCur);
        k_scan<<<3, 1024, 0, stream>>>(inCur, outCur, inOffRaw, pinOff, poutOff);
        hipMemsetAsync(inCur, 0, 2 * N_NODES * sizeof(int), stream);
        hipMemsetAsync(inPrt, 0, 2 * (size_t)PADCAP * sizeof(unsigned short), stream);
        hipMemsetAsync(eaIn, 0, 2 * (size_t)PADCAP * 4 * sizeof(__half), stream);
        k_fill<<<gridE, 256, 0, stream>>>(rowI, colI, inOffRaw, pinOff, poutOff,
                                          inCur, outCur, inL2, poPA, eArr, inPrt, outPrt);

        k_init<<<(N_NODES * HI + 255) / 256, 256, 0, stream>>>(
            x + (size_t)j * N_NODES * 4, inW + j * 128, inb + j * 32, m);

        for (int it = 0; it < 3; ++it) {
            k_gemm5<<<ROWS_P / 32, 320, 0, stream>>>(m, eW1j, nW1j, u, v, p, q, rbuf);
            k_edge<false><<<N_EDGES * 4 / 256, 256, 0, stream>>>(
                inL2, poPA, eArr, u, v, eb1j, eW2j, eb2j, eaIn, eaOut, nullptr);
            k_node<<<N_NODES / 4, 256, 0, stream>>>(m, rbuf, p, q, eaIn, eaOut,
                                                    pinOff, poutOff, inPrt, outPrt,
                                                    nb1j, nW2j, nb2j);
        }
        k_gemm2<<<ROWS_P / 32, 256, 0, stream>>>(m, eW1j, eW1j + 36 * 32, u, v);
        k_edge<true><<<N_EDGES * 4 / 256, 256, 0, stream>>>(
            inL2, poPA, eArr, u, v, eb1j, eW2j, eb2j, nullptr, nullptr,
            out + (size_t)j * N_EDGES * 4);
    }
}